// Round 4
// baseline (130.319 us; speedup 1.0000x reference)
//
#include <hip/hip_runtime.h>

#define B_   4
#define N_   2048
#define DIM  128
#define NH   8
#define HD   16
#define FFN_ 256
#define LN_EPS 1e-5f
#define BN   (B_*N_)
#define LOG2E 1.44269504f
#define RESCALE_THR 12.0f   // log2 units

#if __has_builtin(__builtin_amdgcn_exp2f)
#define EXP2(x) __builtin_amdgcn_exp2f(x)
#else
#define EXP2(x) exp2f(x)
#endif

typedef __bf16 bf16x8 __attribute__((ext_vector_type(8)));
typedef short  s16x8  __attribute__((ext_vector_type(8)));
typedef float  f32x16 __attribute__((ext_vector_type(16)));
typedef unsigned int u32x4 __attribute__((ext_vector_type(4)));

// ROCm clang declares __builtin_amdgcn_mfma_f32_32x32x16_bf16 with either
// <8 x bf16> or <8 x i16> operands depending on version. SFINAE both.
template<class T> struct as_short_vec { using type = s16x8; };

template <class T>
__device__ auto mfma_try(T a, T b, f32x16 c, int)
    -> decltype(__builtin_amdgcn_mfma_f32_32x32x16_bf16(a, b, c, 0, 0, 0)) {
  return __builtin_amdgcn_mfma_f32_32x32x16_bf16(a, b, c, 0, 0, 0);
}
template <class T>
__device__ f32x16 mfma_try(T a, T b, f32x16 c, long) {
  return __builtin_amdgcn_mfma_f32_32x32x16_bf16(
      __builtin_bit_cast(typename as_short_vec<T>::type, a),
      __builtin_bit_cast(typename as_short_vec<T>::type, b), c, 0, 0, 0);
}
__device__ __forceinline__ f32x16 mfma_bf(bf16x8 a, bf16x8 b, f32x16 c) {
  return mfma_try(a, b, c, 0);
}

// ---------------- adj (int32 0/1) -> 64-bit masks ----------------
__global__ __launch_bounds__(256) void k_adjbits(const int* __restrict__ adj,
                                                 unsigned long long* __restrict__ bits) {
    long long idx = (long long)blockIdx.x * 256 + threadIdx.x;
    int v = adj[idx] != 0;
    unsigned long long m = __ballot(v);
    if ((threadIdx.x & 63) == 0) bits[idx >> 6] = m;
}

// ------- expand adj bits into MFMA-fragment-ordered 16-bit AND masks -------
// Mex[((tg*2048+q)*2+hi)*8 + j] : u32 whose low/high 16 bits are 0xFFFF iff
// keys pos(2j),pos(2j+1) of tile tg are unmasked for query q,
// pos(r) = (r&3) + 8*(r>>2) + 4*hi.
__global__ __launch_bounds__(256) void k_adjexp(
    const unsigned long long* __restrict__ adjb, unsigned int* __restrict__ Mex) {
    const int g  = blockIdx.x * 256 + threadIdx.x;   // 64*2048*2 threads
    const int hi = g & 1;
    const int q  = (g >> 1) & 2047;
    const int tg = g >> 12;
    unsigned long long w = adjb[(size_t)q * 32 + (tg >> 1)];
    unsigned mm = (unsigned)(w >> ((tg & 1) * 32));
    const int pbase[8] = {0, 2, 8, 10, 16, 18, 24, 26};
    unsigned int out[8];
    #pragma unroll
    for (int j = 0; j < 8; ++j) {
        int base = pbase[j] + 4 * hi;
        unsigned lo = (mm >> base) & 1u;
        unsigned hb = (mm >> (base + 1)) & 1u;
        out[j] = (lo ? 0xFFFFu : 0u) | (hb ? 0xFFFF0000u : 0u);
    }
    unsigned int* dst = Mex + (size_t)g * 8;
    *(u32x4*)dst       = u32x4{out[0], out[1], out[2], out[3]};
    *(u32x4*)(dst + 4) = u32x4{out[4], out[5], out[6], out[7]};
}

// ------- fill V^T rows 16..31 with bf16 1.0 (sum-via-MFMA ones rows) -------
__global__ __launch_bounds__(256) void k_vones(unsigned short* __restrict__ Vt) {
    const int g  = blockIdx.x * 256 + threadIdx.x;  // 32*4096 threads
    const int bh = g >> 12;
    const int r  = g & 4095;
    uint4* p = (uint4*)Vt;
    uint4 v = {0x3F803F80u, 0x3F803F80u, 0x3F803F80u, 0x3F803F80u};
    p[(size_t)bh * 8192 + 4096 + r] = v;
}

// ---------------- fused QKV projection -> bf16, attention layouts ----------
// Qb,Kb: [B][H][N][HD] bf16 (Q pre-scaled by 0.25*log2e);
// Vt: [B][H][32][N] bf16 (rows 0..15 = V^T with keys permuted per 32-block,
// rows 16..31 = 1.0 written by k_vones).
__global__ __launch_bounds__(256) void k_qkv(const float* __restrict__ h,
    const float* __restrict__ Wq, const float* __restrict__ Wk, const float* __restrict__ Wv,
    __bf16* __restrict__ Qb, __bf16* __restrict__ Kb, __bf16* __restrict__ Vt) {
    __shared__ float hs[16][DIM];
    const int r0  = blockIdx.x * 16;
    const int tid = threadIdx.x;
    for (int i = tid; i < 16 * DIM; i += 256)
        hs[i >> 7][i & 127] = h[(size_t)r0 * DIM + i];
    __syncthreads();
    const int c     = tid & 127;
    const int rbase = (tid >> 7) * 8;
    float aq[8], ak[8], av[8];
    #pragma unroll
    for (int i = 0; i < 8; ++i) { aq[i] = 0.f; ak[i] = 0.f; av[i] = 0.f; }
    for (int k4 = 0; k4 < DIM; k4 += 4) {
        float4 hv[8];
        #pragma unroll
        for (int r = 0; r < 8; ++r) hv[r] = *(const float4*)&hs[rbase + r][k4];
        #pragma unroll
        for (int kk = 0; kk < 4; ++kk) {
            const int k = k4 + kk;
            float wq = Wq[k * DIM + c], wk = Wk[k * DIM + c], wv = Wv[k * DIM + c];
            #pragma unroll
            for (int r = 0; r < 8; ++r) {
                float hvv = ((const float*)&hv[r])[kk];
                aq[r] += hvv * wq; ak[r] += hvv * wk; av[r] += hvv * wv;
            }
        }
    }
    const int hh = c >> 4, d = c & 15;
    const int b  = r0 >> 11;
    const int n0 = (r0 & (N_ - 1)) + rbase;
    size_t qk = ((size_t)(b * NH + hh) * N_ + n0) * HD + d;
    size_t vh = ((size_t)(b * NH + hh) * 32 + d) * N_;
    #pragma unroll
    for (int i = 0; i < 8; ++i) {
        Qb[qk + (size_t)i * HD] = (__bf16)(aq[i] * (0.25f * LOG2E));
        Kb[qk + (size_t)i * HD] = (__bf16)ak[i];
        int n  = n0 + i;
        int g  = (n >> 2) & 7;
        int ng = (g & 4) | ((g & 1) << 1) | ((g >> 1) & 1);
        Vt[vh + ((n & ~31) | (ng << 2) | (n & 3))] = (__bf16)av[i];
    }
}

// ---------------- masked flash attention, MFMA 32x32x16, split-K ----------
// grid: B*H*(N/128) = 512 blocks x 512 thr (8 waves).
// waves 0-3: keys 0..1023 for 128 q-rows; waves 4-7: keys 1024..2047.
__global__ __launch_bounds__(512, 4) void k_attn(
    const __bf16* __restrict__ Qb, const __bf16* __restrict__ Kb,
    const __bf16* __restrict__ Vt, const unsigned int* __restrict__ Mex,
    float* __restrict__ AO) {
    const int bid  = blockIdx.x;
    const int qt   = bid & 15;
    const int hh   = (bid >> 4) & 7;
    const int b    = bid >> 7;
    const int wv   = threadIdx.x >> 6;
    const int wq   = wv & 3;
    const int half = wv >> 2;
    const int lane = threadIdx.x & 63;
    const int l31  = lane & 31, hi = lane >> 5;
    const int q     = qt * 128 + wq * 32 + l31;
    const int kbase = half * (N_ / 2);
    const int NT    = N_ / 64;   // 32 tiles of 32 keys per half

    __shared__ float accL[4][64][9];
    __shared__ float mL[4][32], sL[4][32];

    const __bf16* Qh = Qb + (size_t)(b * NH + hh) * N_ * HD;
    const __bf16* Kh = Kb + (size_t)(b * NH + hh) * N_ * HD;
    // rows 0..15: V^T (key-permuted); rows 16..31: ones (sum rows)
    const __bf16* Vh = Vt + ((size_t)(b * NH + hh) * 32 + l31) * N_;

    // Q^T B-frag: col q = l31, d = hi*8 + i — one 16B load.
    bf16x8 qf = *(const bf16x8*)(Qh + (size_t)q * HD + hi * 8);

    f32x16 acc;
    #pragma unroll
    for (int i = 0; i < 16; ++i) acc[i] = 0.f;
    float m = -1e30f;
    const f32x16 z = {};   // loop-invariant zero C

    const unsigned int* Mp =
        Mex + ((size_t)(half * NT) * 4096 + (size_t)q * 2 + hi) * 8;

    bf16x8 kf  = *(const bf16x8*)(Kh + (size_t)(kbase + l31) * HD + hi * 8);
    bf16x8 vfa = *(const bf16x8*)(Vh + kbase + hi * 8);
    bf16x8 vfb = *(const bf16x8*)(Vh + kbase + 16 + hi * 8);
    u32x4  ma  = *(const u32x4*)Mp;
    u32x4  mb  = *(const u32x4*)(Mp + 4);

    for (int t = 0; t < NT; ++t) {
        // prefetch tile t+1
        bf16x8 kf_n = kf, vfa_n = vfa, vfb_n = vfb;
        u32x4 ma_n = ma, mb_n = mb;
        if (t + 1 < NT) {
            const int k1 = kbase + (t + 1) * 32;
            kf_n  = *(const bf16x8*)(Kh + (size_t)(k1 + l31) * HD + hi * 8);
            vfa_n = *(const bf16x8*)(Vh + k1 + hi * 8);
            vfb_n = *(const bf16x8*)(Vh + k1 + 16 + hi * 8);
            const unsigned int* Mq = Mp + 32768;
            ma_n = *(const u32x4*)Mq;
            mb_n = *(const u32x4*)(Mq + 4);
        }

        // S^T[k][q] (log2-scaled): D: q = l31, k = (r&3)+8*(r>>2)+4*hi
        f32x16 st = mfma_bf(kf, qf, z);

        // tile max over raw scores (masked same distribution: safe)
        float a0 = fmaxf(fmaxf(st[0], st[1]), st[2]);
        float a1 = fmaxf(fmaxf(st[3], st[4]), st[5]);
        float a2 = fmaxf(fmaxf(st[6], st[7]), st[8]);
        float a3 = fmaxf(fmaxf(st[9], st[10]), st[11]);
        float a4 = fmaxf(fmaxf(st[12], st[13]), st[14]);
        float b0 = fmaxf(fmaxf(a0, a1), a2);
        float b1 = fmaxf(fmaxf(a3, a4), st[15]);
        float tm = fmaxf(b0, b1);
        tm = fmaxf(tm, __shfl_xor(tm, 32));

        // deferred rescale (T13): guarantees st - m <= RESCALE_THR after this
        if (__any(tm > m + RESCALE_THR)) {
            float mn = fmaxf(m, tm);
            float sc = EXP2(m - mn);
            #pragma unroll
            for (int r = 0; r < 9; ++r) acc[r] *= sc;
            m = mn;
        }

        // p = 2^(st - m), bounded by 2^12; mask applied on packed bf16 via AND
        float p[16];
        #pragma unroll
        for (int r = 0; r < 16; ++r) p[r] = EXP2(st[r] - m);
        bf16x8 pa, pb;
        #pragma unroll
        for (int r = 0; r < 8; ++r) { pa[r] = (__bf16)p[r]; pb[r] = (__bf16)p[r + 8]; }
        pa = __builtin_bit_cast(bf16x8, __builtin_bit_cast(u32x4, pa) & ma);
        pb = __builtin_bit_cast(bf16x8, __builtin_bit_cast(u32x4, pb) & mb);

        // PV; rows 16..31 of V^T are ones -> acc[8] accumulates sum(p)
        acc = mfma_bf(vfa, pa, acc);
        acc = mfma_bf(vfb, pb, acc);

        kf = kf_n; vfa = vfa_n; vfb = vfb_n; ma = ma_n; mb = mb_n;
        Mp += 32768;
    }

    const float sum = acc[8];

    // ---- split-K merge through LDS ----
    if (half == 0) {
        #pragma unroll
        for (int r = 0; r < 8; ++r) accL[wq][lane][r] = acc[r];
        if (hi == 0) { mL[wq][l31] = m; sL[wq][l31] = sum; }
    }
    __syncthreads();
    if (half == 1) {
        float m0 = mL[wq][l31], s0 = sL[wq][l31];
        float mM = fmaxf(m, m0);
        float e1 = EXP2(m - mM), e0 = EXP2(m0 - mM);
        float s  = s0 * e0 + sum * e1;
        float inv = 1.f / s;
        float o[8];
        #pragma unroll
        for (int r = 0; r < 8; ++r)
            o[r] = (accL[wq][lane][r] * e0 + acc[r] * e1) * inv;
        float* op = AO + ((size_t)(b * N_ + q)) * DIM + hh * HD + 4 * hi;
        float4 o0 = { o[0], o[1], o[2], o[3] };
        float4 o1 = { o[4], o[5], o[6], o[7] };
        *(float4*)op       = o0;   // d = 4*hi + 0..3
        *(float4*)(op + 8) = o1;   // d = 8 + 4*hi + 0..3
    }
}

// ---------------- Wo projection + residual + LN1 ----------------
__global__ __launch_bounds__(128) void k_proj_ln(
    const float* __restrict__ AO, const float* __restrict__ h,
    const float* __restrict__ Wo, const float* __restrict__ bo,
    const float* __restrict__ g, const float* __restrict__ bln,
    float* __restrict__ X) {
    const int r0 = blockIdx.x * 8;
    const int c  = threadIdx.x;
    __shared__ float a[8][DIM];
    __shared__ float vv[8][DIM];
    __shared__ float mu_s[8], rs_s[8];
    for (int i = c; i < 8 * DIM; i += 128)
        a[i >> 7][i & 127] = AO[(long long)r0 * DIM + i];
    __syncthreads();
    float accv[8];
    float bov = bo[c];
    #pragma unroll
    for (int r = 0; r < 8; ++r) accv[r] = bov;
    for (int k = 0; k < DIM; ++k) {
        float w = Wo[k * DIM + c];
        #pragma unroll
        for (int r = 0; r < 8; ++r) accv[r] += a[r][k] * w;
    }
    #pragma unroll
    for (int r = 0; r < 8; ++r)
        vv[r][c] = accv[r] + h[((long long)(r0 + r)) * DIM + c];
    __syncthreads();
    const int wv = c >> 6, ln = c & 63;
    for (int i = 0; i < 4; ++i) {
        int r = wv * 4 + i;
        float x0 = vv[r][ln], x1 = vv[r][ln + 64];
        float s = x0 + x1, s2 = x0 * x0 + x1 * x1;
        for (int off = 1; off < 64; off <<= 1) {
            s  += __shfl_xor(s,  off);
            s2 += __shfl_xor(s2, off);
        }
        if (ln == 0) {
            float mu = s * (1.f / DIM);
            float var = s2 * (1.f / DIM) - mu * mu;
            mu_s[r] = mu; rs_s[r] = rsqrtf(var + LN_EPS);
        }
    }
    __syncthreads();
    float gc = g[c], bc = bln[c];
    #pragma unroll
    for (int r = 0; r < 8; ++r)
        X[((long long)(r0 + r)) * DIM + c] = (vv[r][c] - mu_s[r]) * rs_s[r] * gc + bc;
}

// ---------------- FFN + residual + LN2 ----------------
__global__ __launch_bounds__(256) void k_ffn_ln(
    const float* __restrict__ X,
    const float* __restrict__ W1, const float* __restrict__ b1,
    const float* __restrict__ W2, const float* __restrict__ b2,
    const float* __restrict__ g, const float* __restrict__ bln,
    float* __restrict__ out) {
    const int r0  = blockIdx.x * 8;
    const int tid = threadIdx.x;
    __shared__ float xs[8][DIM];
    __shared__ float ts[8][FFN_];
    __shared__ float vv[8][DIM];
    __shared__ float mu_s[8], rs_s[8];
    for (int i = tid; i < 8 * DIM; i += 256)
        xs[i >> 7][i & 127] = X[(long long)r0 * DIM + i];
    __syncthreads();
    {
        float accv[8];
        float bb = b1[tid];
        #pragma unroll
        for (int r = 0; r < 8; ++r) accv[r] = bb;
        for (int k = 0; k < DIM; ++k) {
            float w = W1[k * FFN_ + tid];
            #pragma unroll
            for (int r = 0; r < 8; ++r) accv[r] += xs[r][k] * w;
        }
        #pragma unroll
        for (int r = 0; r < 8; ++r) ts[r][tid] = fmaxf(accv[r], 0.f);
    }
    __syncthreads();
    {
        const int c = tid & 127, rg = tid >> 7;
        float y[4];
        float bb = b2[c];
        #pragma unroll
        for (int i = 0; i < 4; ++i) y[i] = bb;
        for (int k = 0; k < FFN_; ++k) {
            float w = W2[k * DIM + c];
            #pragma unroll
            for (int i = 0; i < 4; ++i) y[i] += ts[rg * 4 + i][k] * w;
        }
        #pragma unroll
        for (int i = 0; i < 4; ++i) vv[rg * 4 + i][c] = y[i] + xs[rg * 4 + i][c];
    }
    __syncthreads();
    {
        const int wv = tid >> 6, ln = tid & 63;
        for (int i = 0; i < 2; ++i) {
            int rr = wv * 2 + i;
            float x0 = vv[rr][ln], x1 = vv[rr][ln + 64];
            float s = x0 + x1, s2 = x0 * x0 + x1 * x1;
            for (int off = 1; off < 64; off <<= 1) {
                s  += __shfl_xor(s,  off);
                s2 += __shfl_xor(s2, off);
            }
            if (ln == 0) {
                float mu = s * (1.f / DIM);
                float var = s2 * (1.f / DIM) - mu * mu;
                mu_s[rr] = mu; rs_s[rr] = rsqrtf(var + LN_EPS);
            }
        }
    }
    __syncthreads();
    {
        const int c = tid & 127, rg = tid >> 7;
        float gc = g[c], bc = bln[c];
        #pragma unroll
        for (int i = 0; i < 4; ++i) {
            int rr = rg * 4 + i;
            out[((long long)(r0 + rr)) * DIM + c] =
                (vv[rr][c] - mu_s[rr]) * rs_s[rr] * gc + bc;
        }
    }
}

extern "C" void kernel_launch(void* const* d_in, const int* in_sizes, int n_in,
                              void* d_out, int out_size, void* d_ws, size_t ws_size,
                              hipStream_t stream) {
    const int*   adj = (const int*)  d_in[0];
    const float* h   = (const float*)d_in[1];
    const float* Wq  = (const float*)d_in[2];
    const float* Wk  = (const float*)d_in[3];
    const float* Wv  = (const float*)d_in[4];
    const float* Wo  = (const float*)d_in[5];
    const float* bo  = (const float*)d_in[6];
    const float* g1  = (const float*)d_in[7];
    const float* b1l = (const float*)d_in[8];
    const float* W1  = (const float*)d_in[9];
    const float* b1  = (const float*)d_in[10];
    const float* W2  = (const float*)d_in[11];
    const float* b2  = (const float*)d_in[12];
    const float* g2  = (const float*)d_in[13];
    const float* b2l = (const float*)d_in[14];
    float* out = (float*)d_out;

    float* AO = (float*)d_ws;                                  // BN*DIM f32 (4MB)
    float* X  = AO + (size_t)BN * DIM;                         // BN*DIM f32 (4MB)
    unsigned long long* adjb = (unsigned long long*)(X + (size_t)BN * DIM); // 512KB
    unsigned int* Mex = (unsigned int*)(adjb + (size_t)N_ * N_ / 64);       // 8MB
    __bf16* Qb = (__bf16*)(Mex + (size_t)64 * 2048 * 2 * 8);   // 2MB
    __bf16* Kb = Qb + (size_t)BN * DIM;                        // 2MB
    __bf16* Vt = Kb + (size_t)BN * DIM;                        // [B][H][32][N] 4MB

    hipLaunchKernelGGL(k_adjbits, dim3(N_ * N_ / 256), dim3(256), 0, stream, adj, adjb);
    hipLaunchKernelGGL(k_adjexp, dim3(64 * 2048 * 2 / 256), dim3(256), 0, stream,
                       adjb, Mex);
    hipLaunchKernelGGL(k_vones, dim3(B_ * NH * 4096 / 256), dim3(256), 0, stream,
                       (unsigned short*)Vt);
    hipLaunchKernelGGL(k_qkv, dim3(BN / 16), dim3(256), 0, stream, h, Wq, Wk, Wv, Qb, Kb, Vt);
    hipLaunchKernelGGL(k_attn, dim3(B_ * NH * (N_ / 128)), dim3(512), 0, stream,
                       Qb, Kb, Vt, Mex, AO);
    hipLaunchKernelGGL(k_proj_ln, dim3(BN / 8), dim3(128), 0, stream,
                       AO, h, Wo, bo, g1, b1l, X);
    hipLaunchKernelGGL(k_ffn_ln, dim3(BN / 8), dim3(256), 0, stream,
                       X, W1, b1, W2, b2, g2, b2l, out);
}